// Round 8
// baseline (197.424 us; speedup 1.0000x reference)
//
#include <hip/hip_runtime.h>
#include <hip/hip_bf16.h>
#include <math.h>

// Problem constants (fixed by the reference)
constexpr int kB  = 2;
constexpr int kN  = 16384;   // H*W = 128*128
constexpr int kC  = 128;
constexpr int kNr = 1024;    // 32*32 reduced tokens
constexpr float kScale = 0.125f;  // hd^-0.5, hd=64

typedef short bf16x8 __attribute__((ext_vector_type(8)));
typedef float f32x4  __attribute__((ext_vector_type(4)));

__device__ inline ushort f2bf(float x) {
  __hip_bfloat16 h = __float2bfloat16(x);
  return *(ushort*)&h;
}
__device__ inline unsigned pack_bf16(float a, float b) {
  return (unsigned)f2bf(a) | ((unsigned)f2bf(b) << 16);
}
__device__ inline float bf2f(ushort u) {
  unsigned v = ((unsigned)u) << 16;
  return __uint_as_float(v);
}

__device__ inline void transp_body(const float* __restrict__ w,
                                   ushort* __restrict__ wt,
                                   int K, int N, int flat4) {
  int n4pr = N >> 2;
  int k = flat4 / n4pr, n = (flat4 % n4pr) * 4;
  if (k >= K) return;
  float4 v = *(const float4*)&w[(size_t)k * N + n];
  wt[(size_t)(n + 0) * K + k] = f2bf(v.x);
  wt[(size_t)(n + 1) * K + k] = f2bf(v.y);
  wt[(size_t)(n + 2) * K + k] = f2bf(v.z);
  wt[(size_t)(n + 3) * K + k] = f2bf(v.w);
}

// ---------------------------------------------------------------------------
// prep: x->bf16 cast, 4 weight transposes, zsums zero.  One launch.
// blocks: [0,2048) cast | [2048,2064) qwt | [2064,2080) pwt |
//         [2080,2112) kwt | [2112,2368) swt | 2368 zero
// ---------------------------------------------------------------------------
__global__ __launch_bounds__(256) void prep(const float* __restrict__ x,
                                            const float* __restrict__ q_w,
                                            const float* __restrict__ proj_w,
                                            const float* __restrict__ kv_w,
                                            const float* __restrict__ sr_w,
                                            ushort* __restrict__ xbf,
                                            ushort* __restrict__ qwt,
                                            ushort* __restrict__ pwt,
                                            ushort* __restrict__ kwt,
                                            ushort* __restrict__ swt,
                                            float* __restrict__ zsums) {
  int bid = blockIdx.x, t = threadIdx.x;
  if (bid < 2048) {
    int i = (bid * 256 + t) * 8;
    float4 a = *(const float4*)&x[i];
    float4 b = *(const float4*)&x[i + 4];
    uint4 o;
    o.x = pack_bf16(a.x, a.y); o.y = pack_bf16(a.z, a.w);
    o.z = pack_bf16(b.x, b.y); o.w = pack_bf16(b.z, b.w);
    *(uint4*)&xbf[i] = o;
  } else if (bid < 2064) {
    transp_body(q_w, qwt, 128, 128, (bid - 2048) * 256 + t);
  } else if (bid < 2080) {
    transp_body(proj_w, pwt, 128, 128, (bid - 2064) * 256 + t);
  } else if (bid < 2112) {
    transp_body(kv_w, kwt, 128, 256, (bid - 2080) * 256 + t);
  } else if (bid < 2368) {
    transp_body(sr_w, swt, 2048, 128, (bid - 2112) * 256 + t);
  } else {
    zsums[t] = 0.f;
    zsums[256 + t] = 0.f;
  }
}

// ---------------------------------------------------------------------------
// MFMA GEMM: qbf = bf16( (xbf @ q_w) * kScale ).  M=32768, K=N=128.
// ---------------------------------------------------------------------------
__global__ __launch_bounds__(256) void gemm_q_mfma(const ushort* __restrict__ xbf,
                                                   const ushort* __restrict__ wt,
                                                   ushort* __restrict__ Cbf) {
  __shared__ __align__(16) char Bs[32768];  // [128n][128k] bf16, XOR-swizzled
  const int t = threadIdx.x, l = t & 63, w = t >> 6, c = l & 15, lg = l >> 4;
  const int m0 = blockIdx.x * 64;
#pragma unroll
  for (int r = 0; r < 8; ++r) {
    int sf = r * 256 + t;             // 0..2047 16B-slots
    int n = sf >> 4, sl = sf & 15;
    uint4 v = *(const uint4*)(wt + n * 128 + sl * 8);
    *(uint4*)(Bs + ((n * 256 + sl * 16) ^ ((n & 7) << 4))) = v;
  }
  __syncthreads();
  const int mrow = m0 + 16 * w + c;
  f32x4 acc[8];
#pragma unroll
  for (int i = 0; i < 8; ++i) acc[i] = f32x4{0.f, 0.f, 0.f, 0.f};
#pragma unroll
  for (int ks = 0; ks < 4; ++ks) {
    bf16x8 af = *(const bf16x8*)(xbf + (size_t)mrow * 128 + ks * 32 + 8 * lg);
#pragma unroll
    for (int nt = 0; nt < 8; ++nt) {
      int n = 16 * nt + c;
      bf16x8 bf = *(const bf16x8*)(Bs + ((n * 256 + 64 * ks + 16 * lg) ^ ((n & 7) << 4)));
      acc[nt] = __builtin_amdgcn_mfma_f32_16x16x32_bf16(af, bf, acc[nt], 0, 0, 0);
    }
  }
#pragma unroll
  for (int nt = 0; nt < 8; ++nt) {
    int col = 16 * nt + c;
#pragma unroll
    for (int r = 0; r < 4; ++r)
      Cbf[(size_t)(m0 + 16 * w + 4 * lg + r) * 128 + col] = f2bf(acc[nt][r] * kScale);
  }
}

// ---------------------------------------------------------------------------
// Fused conv(4x4/s4) -> LayerNorm -> kv GEMM.  128 blocks, 16 patches each.
// Phase 1: MFMA patch-GEMM (wave w = cols w*32..+32), fp32 -> LDS + bias.
// Phase 2: per-row LN (16 threads/row, shuffle reduce) -> bf16 LDS (swizzled).
// Phase 3: MFMA kv GEMM (wave w = kv cols w*64..+64), B from L2-resident kwt.
// Writes compact per-head kbf [b,h][tok][64], vbf [b,h][tok][64],
// and pre-transposed vtbf [b,h][64][1024].  No xr / kvb round trips.
// ---------------------------------------------------------------------------
__global__ __launch_bounds__(256) void convlnkv(const ushort* __restrict__ xbf,
                                                const ushort* __restrict__ swt,
                                                const float* __restrict__ sr_b,
                                                const float* __restrict__ ln_g,
                                                const float* __restrict__ ln_b,
                                                const ushort* __restrict__ kwt,
                                                ushort* __restrict__ kbf,
                                                ushort* __restrict__ vtbf,
                                                ushort* __restrict__ vbf) {
  __shared__ float Lf[16][132];                 // conv + bias, fp32
  __shared__ __align__(16) char Lbf[4096];      // LN'd bf16 [16][128], swizzled
  const int t = threadIdx.x, l = t & 63, w = t >> 6, c = l & 15, lg = l >> 4;
  const int m0 = blockIdx.x * 16;
  const int p = m0 + c;
  const int pb_ = p >> 10, hr = (p & 1023) >> 5, wr = p & 31;

  // ---- phase 1: conv ----
  f32x4 acc[2];
  acc[0] = f32x4{0.f, 0.f, 0.f, 0.f};
  acc[1] = f32x4{0.f, 0.f, 0.f, 0.f};
  for (int tp = 0; tp < 16; ++tp) {
    int ti = tp >> 2, tj = tp & 3;
    const ushort* ap =
        xbf + (size_t)((pb_ * 128 + hr * 4 + ti) * 128 + wr * 4 + tj) * 128;
#pragma unroll
    for (int ks = 0; ks < 4; ++ks) {
      bf16x8 af = *(const bf16x8*)(ap + ks * 32 + 8 * lg);
#pragma unroll
      for (int nt = 0; nt < 2; ++nt) {
        int n = w * 32 + 16 * nt + c;
        bf16x8 bf = *(const bf16x8*)(swt + (size_t)n * 2048 + tp * 128 + ks * 32 + 8 * lg);
        acc[nt] = __builtin_amdgcn_mfma_f32_16x16x32_bf16(af, bf, acc[nt], 0, 0, 0);
      }
    }
  }
#pragma unroll
  for (int nt = 0; nt < 2; ++nt)
#pragma unroll
    for (int r = 0; r < 4; ++r) {
      int col = w * 32 + 16 * nt + c;
      Lf[4 * lg + r][col] = acc[nt][r] + sr_b[col];
    }
  __syncthreads();

  // ---- phase 2: LayerNorm (row = t>>4, 8 cols each) ----
  {
    int row = t >> 4, c8 = (t & 15) * 8;
    float v[8];
    float s = 0.f, sq = 0.f;
#pragma unroll
    for (int j = 0; j < 8; ++j) {
      v[j] = Lf[row][c8 + j];
      s += v[j]; sq += v[j] * v[j];
    }
#pragma unroll
    for (int off = 1; off < 16; off <<= 1) {
      s  += __shfl_xor(s, off, 64);
      sq += __shfl_xor(sq, off, 64);
    }
    float mu  = s * (1.f / 128.f);
    float var = sq * (1.f / 128.f) - mu * mu;
    float inv = 1.0f / sqrtf(var + 1e-5f);
    uint4 pk;
    unsigned* pu = (unsigned*)&pk;
#pragma unroll
    for (int j2 = 0; j2 < 4; ++j2) {
      float a = (v[2 * j2]     - mu) * inv * ln_g[c8 + 2 * j2]     + ln_b[c8 + 2 * j2];
      float b = (v[2 * j2 + 1] - mu) * inv * ln_g[c8 + 2 * j2 + 1] + ln_b[c8 + 2 * j2 + 1];
      pu[j2] = pack_bf16(a, b);
    }
    *(uint4*)(Lbf + ((row * 256 + c8 * 2) ^ ((row & 7) << 4))) = pk;
  }
  __syncthreads();

  // ---- phase 3: kv GEMM (wave w = kv cols w*64..+64, 4 nt) ----
  f32x4 a2[4];
#pragma unroll
  for (int i = 0; i < 4; ++i) a2[i] = f32x4{0.f, 0.f, 0.f, 0.f};
#pragma unroll
  for (int ks = 0; ks < 4; ++ks) {
    bf16x8 af = *(const bf16x8*)(Lbf + ((c * 256 + ks * 64 + 16 * lg) ^ ((c & 7) << 4)));
#pragma unroll
    for (int nt = 0; nt < 4; ++nt) {
      int n = w * 64 + 16 * nt + c;
      bf16x8 bf = *(const bf16x8*)(kwt + (size_t)n * 128 + ks * 32 + 8 * lg);
      a2[nt] = __builtin_amdgcn_mfma_f32_16x16x32_bf16(af, bf, a2[nt], 0, 0, 0);
    }
  }
#pragma unroll
  for (int nt = 0; nt < 4; ++nt)
#pragma unroll
    for (int r = 0; r < 4; ++r) {
      int m = m0 + 4 * lg + r;
      int b = m >> 10, tok = m & 1023;
      int n = w * 64 + 16 * nt + c;
      ushort val = f2bf(a2[nt][r]);
      if (n < 128) {
        int h = n >> 6, dl = n & 63;
        kbf[((size_t)((b * 2 + h) * 1024 + tok)) * 64 + dl] = val;
      } else {
        int d = n - 128, h = d >> 6, dl = d & 63;
        vbf[((size_t)((b * 2 + h) * 1024 + tok)) * 64 + dl] = val;
        vtbf[((size_t)((b * 2 + h) * 64 + dl)) * 1024 + tok] = val;
      }
    }
}

// ---------------------------------------------------------------------------
// MFMA flash attention: no max-tracking, double-buffered K/V staging,
// one barrier/chunk; epilogue also reduces xg column sums into zsums.
// ---------------------------------------------------------------------------
__global__ __launch_bounds__(256) void attn_mfma(const ushort* __restrict__ qbf,
                                                 const ushort* __restrict__ kbf,
                                                 const ushort* __restrict__ vtbf,
                                                 ushort* __restrict__ xgbf,
                                                 float* __restrict__ zsums) {
  __shared__ __align__(16) char sm[49152];
  // [0,8K) K0 | [8K,16K) V0 | [16K,24K) K1 | [24K,32K) V1 | [32K,48K) P per-wave
  const int t = threadIdx.x;
  const int l = t & 63, w = t >> 6;
  const int c = l & 15, lg = l >> 4;
  const int h = blockIdx.y, b = blockIdx.z;
  const int qb = blockIdx.x * 128;
  char* Pw = sm + 32768 + w * 4096;
  const size_t bh = (size_t)(b * 2 + h);

  const int f0 = t, f1 = 256 + t;
  const int kk0 = f0 >> 3, sl0 = f0 & 7, kk1 = f1 >> 3, sl1 = f1 & 7;
  const int d0 = (kk0 * 128 + sl0 * 16) ^ ((kk0 & 7) << 4);
  const int d1 = (kk1 * 128 + sl1 * 16) ^ ((kk1 & 7) << 4);
  const ushort* ksrc0 = kbf + (bh * 1024 + kk0) * 64 + sl0 * 8;   // +cc*4096
  const ushort* ksrc1 = kbf + (bh * 1024 + kk1) * 64 + sl1 * 8;
  const ushort* vsrc0 = vtbf + (bh * 64 + kk0) * 1024 + sl0 * 8;  // +cc*64
  const ushort* vsrc1 = vtbf + (bh * 64 + kk1) * 1024 + sl1 * 8;

  bf16x8 qf[2][2];
#pragma unroll
  for (int n = 0; n < 2; ++n)
#pragma unroll
    for (int f = 0; f < 2; ++f) {
      size_t off = ((size_t)(b * kN + qb + 32 * w + 16 * n + c)) * 128
                   + h * 64 + 32 * f + 8 * lg;
      qf[n][f] = *(const bf16x8*)(qbf + off);
    }

  float l_run[2] = {0.f, 0.f};
  f32x4 o[2][4] = {};

  {
    uint4 k0 = *(const uint4*)ksrc0;
    uint4 k1 = *(const uint4*)ksrc1;
    uint4 v0 = *(const uint4*)vsrc0;
    uint4 v1 = *(const uint4*)vsrc1;
    *(uint4*)(sm + d0) = k0;        *(uint4*)(sm + d1) = k1;
    *(uint4*)(sm + 8192 + d0) = v0; *(uint4*)(sm + 8192 + d1) = v1;
  }
  __syncthreads();

  int cur = 0;
  for (int cc = 0; cc < 16; ++cc) {
    char* Kb = sm + cur * 16384;
    char* Vb = Kb + 8192;
    uint4 nk0, nk1, nv0, nv1;
    if (cc < 15) {
      nk0 = *(const uint4*)(ksrc0 + (cc + 1) * 4096);
      nk1 = *(const uint4*)(ksrc1 + (cc + 1) * 4096);
      nv0 = *(const uint4*)(vsrc0 + (cc + 1) * 64);
      nv1 = *(const uint4*)(vsrc1 + (cc + 1) * 64);
    }

    bf16x8 kf[4][2];
#pragma unroll
    for (int kt = 0; kt < 4; ++kt)
#pragma unroll
      for (int f = 0; f < 2; ++f) {
        int row = kt * 16 + c;
        kf[kt][f] = *(const bf16x8*)(Kb + ((row * 128 + 64 * f + 16 * lg)
                                           ^ ((row & 7) << 4)));
      }

#pragma unroll
    for (int n = 0; n < 2; ++n) {
      f32x4 s4[4];
#pragma unroll
      for (int kt = 0; kt < 4; ++kt) {
        f32x4 z = {0.f, 0.f, 0.f, 0.f};
        z = __builtin_amdgcn_mfma_f32_16x16x32_bf16(kf[kt][0], qf[n][0], z, 0, 0, 0);
        s4[kt] = __builtin_amdgcn_mfma_f32_16x16x32_bf16(kf[kt][1], qf[n][1], z, 0, 0, 0);
      }
      float psum = 0.f;
#pragma unroll
      for (int kt = 0; kt < 4; ++kt)
#pragma unroll
        for (int r = 0; r < 4; ++r) {
          float p = __expf(s4[kt][r]);
          s4[kt][r] = p; psum += p;
        }
      psum += __shfl_xor(psum, 16, 64);
      psum += __shfl_xor(psum, 32, 64);
      l_run[n] += psum;
      int qq = 16 * n + c;
#pragma unroll
      for (int kt = 0; kt < 4; ++kt) {
        uint2 pk2;
        pk2.x = pack_bf16(s4[kt][0], s4[kt][1]);
        pk2.y = pack_bf16(s4[kt][2], s4[kt][3]);
        *(uint2*)(Pw + ((qq * 128 + 32 * kt + 8 * lg) ^ ((qq & 7) << 4))) = pk2;
      }
    }

    bf16x8 pf[2][2];
#pragma unroll
    for (int n = 0; n < 2; ++n)
#pragma unroll
      for (int hh = 0; hh < 2; ++hh) {
        int qq = 16 * n + c;
        pf[n][hh] = *(const bf16x8*)(Pw + ((qq * 128 + 64 * hh + 16 * lg)
                                           ^ ((qq & 7) << 4)));
      }
#pragma unroll
    for (int dt = 0; dt < 4; ++dt) {
      bf16x8 vf[2];
#pragma unroll
      for (int hh = 0; hh < 2; ++hh) {
        int row = 16 * dt + c;
        vf[hh] = *(const bf16x8*)(Vb + ((row * 128 + 64 * hh + 16 * lg)
                                        ^ ((row & 7) << 4)));
      }
#pragma unroll
      for (int n = 0; n < 2; ++n) {
        f32x4 acc = o[n][dt];
        acc = __builtin_amdgcn_mfma_f32_16x16x32_bf16(pf[n][0], vf[0], acc, 0, 0, 0);
        o[n][dt] = __builtin_amdgcn_mfma_f32_16x16x32_bf16(pf[n][1], vf[1], acc, 0, 0, 0);
      }
    }

    if (cc < 15) {
      char* Kn = sm + (cur ^ 1) * 16384;
      char* Vn = Kn + 8192;
      *(uint4*)(Kn + d0) = nk0; *(uint4*)(Kn + d1) = nk1;
      *(uint4*)(Vn + d0) = nv0; *(uint4*)(Vn + d1) = nv1;
    }
    __syncthreads();
    cur ^= 1;
  }

  // ---- epilogue: normalize, store bf16, reduce column sums ----
  float cs[4] = {0.f, 0.f, 0.f, 0.f};
#pragma unroll
  for (int n = 0; n < 2; ++n) {
    float i0 = 1.f / __shfl(l_run[n], 4 * lg + 0, 64);
    float i1 = 1.f / __shfl(l_run[n], 4 * lg + 1, 64);
    float i2 = 1.f / __shfl(l_run[n], 4 * lg + 2, 64);
    float i3 = 1.f / __shfl(l_run[n], 4 * lg + 3, 64);
#pragma unroll
    for (int dt = 0; dt < 4; ++dt) {
      float v0 = o[n][dt][0] * i0, v1 = o[n][dt][1] * i1;
      float v2 = o[n][dt][2] * i2, v3 = o[n][dt][3] * i3;
      int dg = h * 64 + 16 * dt + c;
      size_t base = ((size_t)(b * kN + qb + 32 * w + 16 * n + 4 * lg)) * 128 + dg;
      xgbf[base]       = f2bf(v0);
      xgbf[base + 128] = f2bf(v1);
      xgbf[base + 256] = f2bf(v2);
      xgbf[base + 384] = f2bf(v3);
      cs[dt] += v0 + v1 + v2 + v3;
    }
  }
#pragma unroll
  for (int dt = 0; dt < 4; ++dt) {
    cs[dt] += __shfl_xor(cs[dt], 16, 64);
    cs[dt] += __shfl_xor(cs[dt], 32, 64);
  }
  float* Cs = (float*)sm;   // [4 waves][64 cols] — safe after final barrier
  if (l < 16) {
#pragma unroll
    for (int dt = 0; dt < 4; ++dt) Cs[w * 64 + dt * 16 + l] = cs[dt];
  }
  __syncthreads();
  if (t < 64) {
    float s = Cs[t] + Cs[64 + t] + Cs[128 + t] + Cs[192 + t];
    atomicAdd(&zsums[b * 256 + h * 64 + t], s);
  }
}

// ---------------------------------------------------------------------------
// Local window attention (bf16 K/V inputs); also reduces xl column sums via
// the exact factorization  sum_q xl[q][c] = sum_k (sum_q P[q][k]) * V[k][c].
// ---------------------------------------------------------------------------
__global__ __launch_bounds__(256) void local_attn(const ushort* __restrict__ qbf,
                                                  const ushort* __restrict__ kbf,
                                                  const ushort* __restrict__ vbf,
                                                  ushort* __restrict__ xlbf,
                                                  float* __restrict__ zsums) {
  __shared__ float Qw[64][132];
  __shared__ float Kw[4][132];
  __shared__ float Vw[4][132];
  __shared__ float Pw[64][4];
  __shared__ float cwp[4][4];
  const int t = threadIdx.x;
  const int l = t & 63, w = t >> 6;
  const int wi = blockIdx.x;
  const int b = wi >> 8, wrem = wi & 255, wy = wrem >> 4, wx = wrem & 15;

#pragma unroll
  for (int r = 0; r < 4; ++r) {
    int flat = r * 256 + t;              // 0..1023
    int tok = flat >> 4, g8 = (flat & 15) * 8;
    int sy = tok >> 3, sx = tok & 7;
    int n = (wy * 8 + sy) * 128 + wx * 8 + sx;
    uint4 v = *(const uint4*)(qbf + ((size_t)(b * kN + n)) * 128 + g8);
    ushort* us = (ushort*)&v;
    Qw[tok][g8 + 0] = bf2f(us[0]); Qw[tok][g8 + 1] = bf2f(us[1]);
    Qw[tok][g8 + 2] = bf2f(us[2]); Qw[tok][g8 + 3] = bf2f(us[3]);
    Qw[tok][g8 + 4] = bf2f(us[4]); Qw[tok][g8 + 5] = bf2f(us[5]);
    Qw[tok][g8 + 6] = bf2f(us[6]); Qw[tok][g8 + 7] = bf2f(us[7]);
  }
  {
    int half = t >> 7, tt = t & 127;
    int tok = tt >> 5, g = (tt & 31) * 4;
    int sy = tok >> 1, sx = tok & 1;
    int kr = (wy * 2 + sy) * 32 + wx * 2 + sx;
    int h = g >> 6, dl = g & 63;
    const ushort* src = (half ? vbf : kbf) + ((size_t)((b * 2 + h) * 1024 + kr)) * 64 + dl;
    uint2 v2 = *(const uint2*)src;
    ushort* us = (ushort*)&v2;
    float4 f = make_float4(bf2f(us[0]), bf2f(us[1]), bf2f(us[2]), bf2f(us[3]));
    if (half == 0) *(float4*)&Kw[tok][g] = f;
    else           *(float4*)&Vw[tok][g] = f;
  }
  __syncthreads();

  {
    int r = t >> 2, kk = t & 3;
    float s = 0.f;
#pragma unroll
    for (int g = 0; g < 128; g += 4) {
      float4 a  = *(const float4*)&Qw[r][g];
      float4 bb = *(const float4*)&Kw[kk][g];
      s += a.x * bb.x + a.y * bb.y + a.z * bb.z + a.w * bb.w;
    }
    float m = s;
    m = fmaxf(m, __shfl_xor(m, 1, 64));
    m = fmaxf(m, __shfl_xor(m, 2, 64));
    float e = __expf(s - m);
    float sum = e;
    sum += __shfl_xor(sum, 1, 64);
    sum += __shfl_xor(sum, 2, 64);
    Pw[r][kk] = e / sum;
  }
  __syncthreads();

  // column-sum part A: colP[k] = sum_q Pw[q][k] (wave partials -> cwp)
  {
    float pv = Pw[t >> 2][t & 3];
    pv += __shfl_xor(pv, 4, 64);
    pv += __shfl_xor(pv, 8, 64);
    pv += __shfl_xor(pv, 16, 64);
    pv += __shfl_xor(pv, 32, 64);
    if (l < 4) cwp[w][l] = pv;
  }

  {
    int r = t >> 2, cg = (t & 3) * 32;
    float p0 = Pw[r][0], p1 = Pw[r][1], p2 = Pw[r][2], p3 = Pw[r][3];
    int sy = r >> 3, sx = r & 7;
    int n = (wy * 8 + sy) * 128 + wx * 8 + sx;
    ushort* dst = &xlbf[((size_t)(b * kN + n)) * 128 + cg];
#pragma unroll
    for (int g = 0; g < 32; g += 4) {
      float4 v0 = *(const float4*)&Vw[0][cg + g];
      float4 v1 = *(const float4*)&Vw[1][cg + g];
      float4 v2 = *(const float4*)&Vw[2][cg + g];
      float4 v3 = *(const float4*)&Vw[3][cg + g];
      float ox = p0 * v0.x + p1 * v1.x + p2 * v2.x + p3 * v3.x;
      float oy = p0 * v0.y + p1 * v1.y + p2 * v2.y + p3 * v3.y;
      float oz = p0 * v0.z + p1 * v1.z + p2 * v2.z + p3 * v3.z;
      float ow = p0 * v0.w + p1 * v1.w + p2 * v2.w + p3 * v3.w;
      uint2 pk;
      pk.x = pack_bf16(ox, oy); pk.y = pack_bf16(oz, ow);
      *(uint2*)&dst[g] = pk;
    }
  }
  __syncthreads();

  // column-sum part B
  if (t < 128) {
    float p0 = cwp[0][0] + cwp[1][0] + cwp[2][0] + cwp[3][0];
    float p1 = cwp[0][1] + cwp[1][1] + cwp[2][1] + cwp[3][1];
    float p2 = cwp[0][2] + cwp[1][2] + cwp[2][2] + cwp[3][2];
    float p3 = cwp[0][3] + cwp[1][3] + cwp[2][3] + cwp[3][3];
    float s = p0 * Vw[0][t] + p1 * Vw[1][t] + p2 * Vw[2][t] + p3 * Vw[3][t];
    atomicAdd(&zsums[b * 256 + 128 + t], s);
  }
}

// Gating MLP, one block per batch element.
__global__ __launch_bounds__(256) void gate_mlp(const float* __restrict__ zsums,
                                                const float* __restrict__ f1w,
                                                const float* __restrict__ f1b,
                                                const float* __restrict__ f2w,
                                                const float* __restrict__ f2b,
                                                float* __restrict__ gates) {
  __shared__ float z[256];
  __shared__ float hbuf[64];
  int b = blockIdx.x, t = threadIdx.x;
  z[t] = zsums[b * 256 + t] * (1.0f / 16384.0f);
  __syncthreads();
  if (t < 64) {
    float a = f1b[t];
    for (int j = 0; j < 256; ++j) a += z[j] * f1w[j * 64 + t];
    hbuf[t] = fmaxf(a, 0.f);
  }
  __syncthreads();
  {
    float a = f2b[t];
    for (int j = 0; j < 64; ++j) a += hbuf[j] * f2w[j * 256 + t];
    gates[b * 256 + t] = 1.f / (1.f + __expf(-a));
  }
}

// ---------------------------------------------------------------------------
// MFMA fused gating + output projection from bf16 xg/xl.
// ---------------------------------------------------------------------------
__global__ __launch_bounds__(256) void fused_proj_mfma(const ushort* __restrict__ xgbf,
                                                       const ushort* __restrict__ xlbf,
                                                       const float* __restrict__ gates,
                                                       const ushort* __restrict__ pwt,
                                                       const float* __restrict__ pb,
                                                       float* __restrict__ out) {
  __shared__ __align__(16) char Bs[32768];
  __shared__ float Gg[128], Gl[128];
  const int t = threadIdx.x, l = t & 63, w = t >> 6, c = l & 15, lg = l >> 4;
  const int m0 = blockIdx.x * 64;
  const int b = m0 >> 14;
#pragma unroll
  for (int r = 0; r < 8; ++r) {
    int sf = r * 256 + t;
    int n = sf >> 4, sl = sf & 15;
    uint4 v = *(const uint4*)(pwt + n * 128 + sl * 8);
    *(uint4*)(Bs + ((n * 256 + sl * 16) ^ ((n & 7) << 4))) = v;
  }
  if (t < 128) Gg[t] = gates[b * 256 + t];
  else         Gl[t - 128] = gates[b * 256 + t];
  __syncthreads();
  const int mrow = m0 + 16 * w + c;
  f32x4 acc[8];
#pragma unroll
  for (int i = 0; i < 8; ++i) acc[i] = f32x4{0.f, 0.f, 0.f, 0.f};
#pragma unroll
  for (int ks = 0; ks < 4; ++ks) {
    int k8 = ks * 32 + 8 * lg;
    uint4 gv = *(const uint4*)(xgbf + (size_t)mrow * 128 + k8);
    uint4 lv = *(const uint4*)(xlbf + (size_t)mrow * 128 + k8);
    ushort* gu = (ushort*)&gv; ushort* lu = (ushort*)&lv;
    float f[8];
#pragma unroll
    for (int j = 0; j < 8; ++j)
      f[j] = Gg[k8 + j] * bf2f(gu[j]) + Gl[k8 + j] * bf2f(lu[j]);
    union { bf16x8 v; unsigned u[4]; } au;
    au.u[0] = pack_bf16(f[0], f[1]); au.u[1] = pack_bf16(f[2], f[3]);
    au.u[2] = pack_bf16(f[4], f[5]); au.u[3] = pack_bf16(f[6], f[7]);
#pragma unroll
    for (int nt = 0; nt < 8; ++nt) {
      int n = 16 * nt + c;
      bf16x8 bf = *(const bf16x8*)(Bs + ((n * 256 + 64 * ks + 16 * lg) ^ ((n & 7) << 4)));
      acc[nt] = __builtin_amdgcn_mfma_f32_16x16x32_bf16(au.v, bf, acc[nt], 0, 0, 0);
    }
  }
#pragma unroll
  for (int nt = 0; nt < 8; ++nt) {
    int col = 16 * nt + c;
    float bias = pb[col];
#pragma unroll
    for (int r = 0; r < 4; ++r)
      out[(size_t)(m0 + 16 * w + 4 * lg + r) * 128 + col] = acc[nt][r] + bias;
  }
}

extern "C" void kernel_launch(void* const* d_in, const int* in_sizes, int n_in,
                              void* d_out, int out_size, void* d_ws, size_t ws_size,
                              hipStream_t stream) {
  const float* x      = (const float*)d_in[0];
  const float* q_w    = (const float*)d_in[1];
  const float* kv_w   = (const float*)d_in[2];
  const float* sr_w   = (const float*)d_in[3];
  const float* sr_b   = (const float*)d_in[4];
  const float* ln_g   = (const float*)d_in[5];
  const float* ln_b   = (const float*)d_in[6];
  const float* proj_w = (const float*)d_in[7];
  const float* proj_b = (const float*)d_in[8];
  const float* f1_w   = (const float*)d_in[9];
  const float* f1_b   = (const float*)d_in[10];
  const float* f2_w   = (const float*)d_in[11];
  const float* f2_b   = (const float*)d_in[12];
  float* out = (float*)d_out;

  float* ws = (float*)d_ws;
  float* zsums = ws;                       //       512 f32
  float* gates = zsums + 512;              //       512 f32
  ushort* xbf  = (ushort*)(gates + 512);   // 4,194,304 bf16 (x copy)
  ushort* qbf  = xbf + 4194304;            // 4,194,304 bf16 (pre-scaled by 0.125)
  ushort* kbf  = qbf + 4194304;            //   262,144 bf16 [b,h][1024][64]
  ushort* vtbf = kbf + 262144;             //   262,144 bf16 [b,h][64][1024]
  ushort* vbf  = vtbf + 262144;            //   262,144 bf16 [b,h][1024][64]
  ushort* xgbf = vbf + 262144;             // 4,194,304 bf16
  ushort* xlbf = xgbf + 4194304;           // 4,194,304 bf16
  ushort* qwt  = xlbf + 4194304;           //    16,384 bf16 q_w^T
  ushort* pwt  = qwt + 16384;              //    16,384 bf16 proj_w^T
  ushort* kwt  = pwt + 16384;              //    32,768 bf16 kv_w^T [256][128]
  ushort* swt  = kwt + 32768;              //   262,144 bf16 sr_w^T [cout][2048]

  // 1. all preps in one launch (cast, 4 transposes, zsums zero)
  prep<<<dim3(2369), 256, 0, stream>>>(x, q_w, proj_w, kv_w, sr_w,
                                       xbf, qwt, pwt, kwt, swt, zsums);
  // 2. qbf = bf16((x @ q_w) * scale)
  gemm_q_mfma<<<dim3(512), 256, 0, stream>>>(xbf, qwt, qbf);
  // 3. conv -> LN -> kv GEMM fused (emits kbf, vtbf, vbf)
  convlnkv<<<dim3(128), 256, 0, stream>>>(xbf, swt, sr_b, ln_g, ln_b, kwt,
                                          kbf, vtbf, vbf);
  // 4. global attention (+ xg column sums)
  attn_mfma<<<dim3(128, 2, 2), 256, 0, stream>>>(qbf, kbf, vtbf, xgbf, zsums);
  // 5. local window attention (+ xl column sums)
  local_attn<<<dim3(512), 256, 0, stream>>>(qbf, kbf, vbf, xlbf, zsums);
  // 6. gate MLP
  gate_mlp<<<dim3(2), 256, 0, stream>>>(zsums, f1_w, f1_b, f2_w, f2_b, gates);
  // 7. fused gating + output projection
  fused_proj_mfma<<<dim3(512), 256, 0, stream>>>(xgbf, xlbf, gates, pwt, proj_b, out);
}

// Round 11
// 195.623 us; speedup vs baseline: 1.0092x; 1.0092x over previous
//
#include <hip/hip_runtime.h>
#include <hip/hip_bf16.h>
#include <math.h>

// Problem constants (fixed by the reference)
constexpr int kB  = 2;
constexpr int kN  = 16384;   // H*W = 128*128
constexpr int kC  = 128;
constexpr int kNr = 1024;    // 32*32 reduced tokens
constexpr float kScale = 0.125f;  // hd^-0.5, hd=64

typedef short bf16x8 __attribute__((ext_vector_type(8)));
typedef float f32x4  __attribute__((ext_vector_type(4)));

__device__ inline ushort f2bf(float x) {
  __hip_bfloat16 h = __float2bfloat16(x);
  return *(ushort*)&h;
}
__device__ inline unsigned pack_bf16(float a, float b) {
  return (unsigned)f2bf(a) | ((unsigned)f2bf(b) << 16);
}
__device__ inline float bf2f(ushort u) {
  unsigned v = ((unsigned)u) << 16;
  return __uint_as_float(v);
}

__device__ inline void transp_body(const float* __restrict__ w,
                                   ushort* __restrict__ wt,
                                   int K, int N, int flat4) {
  int n4pr = N >> 2;
  int k = flat4 / n4pr, n = (flat4 % n4pr) * 4;
  if (k >= K) return;
  float4 v = *(const float4*)&w[(size_t)k * N + n];
  wt[(size_t)(n + 0) * K + k] = f2bf(v.x);
  wt[(size_t)(n + 1) * K + k] = f2bf(v.y);
  wt[(size_t)(n + 2) * K + k] = f2bf(v.z);
  wt[(size_t)(n + 3) * K + k] = f2bf(v.w);
}

// ---------------------------------------------------------------------------
// prep: x->bf16 cast, 4 weight transposes, zsums zero.  One launch.
// ---------------------------------------------------------------------------
__global__ __launch_bounds__(256) void prep(const float* __restrict__ x,
                                            const float* __restrict__ q_w,
                                            const float* __restrict__ proj_w,
                                            const float* __restrict__ kv_w,
                                            const float* __restrict__ sr_w,
                                            ushort* __restrict__ xbf,
                                            ushort* __restrict__ qwt,
                                            ushort* __restrict__ pwt,
                                            ushort* __restrict__ kwt,
                                            ushort* __restrict__ swt,
                                            float* __restrict__ zsums) {
  int bid = blockIdx.x, t = threadIdx.x;
  if (bid < 2048) {
    int i = (bid * 256 + t) * 8;
    float4 a = *(const float4*)&x[i];
    float4 b = *(const float4*)&x[i + 4];
    uint4 o;
    o.x = pack_bf16(a.x, a.y); o.y = pack_bf16(a.z, a.w);
    o.z = pack_bf16(b.x, b.y); o.w = pack_bf16(b.z, b.w);
    *(uint4*)&xbf[i] = o;
  } else if (bid < 2064) {
    transp_body(q_w, qwt, 128, 128, (bid - 2048) * 256 + t);
  } else if (bid < 2080) {
    transp_body(proj_w, pwt, 128, 128, (bid - 2064) * 256 + t);
  } else if (bid < 2112) {
    transp_body(kv_w, kwt, 128, 256, (bid - 2080) * 256 + t);
  } else if (bid < 2368) {
    transp_body(sr_w, swt, 2048, 128, (bid - 2112) * 256 + t);
  } else {
    zsums[t] = 0.f;
    zsums[256 + t] = 0.f;
  }
}

// ---------------------------------------------------------------------------
// MFMA GEMM: qbf = bf16( (xbf @ q_w) * kScale ).  M=32768, K=N=128.
// ---------------------------------------------------------------------------
__global__ __launch_bounds__(256) void gemm_q_mfma(const ushort* __restrict__ xbf,
                                                   const ushort* __restrict__ wt,
                                                   ushort* __restrict__ Cbf) {
  __shared__ __align__(16) char Bs[32768];  // [128n][128k] bf16, XOR-swizzled
  const int t = threadIdx.x, l = t & 63, w = t >> 6, c = l & 15, lg = l >> 4;
  const int m0 = blockIdx.x * 64;
#pragma unroll
  for (int r = 0; r < 8; ++r) {
    int sf = r * 256 + t;             // 0..2047 16B-slots
    int n = sf >> 4, sl = sf & 15;
    uint4 v = *(const uint4*)(wt + n * 128 + sl * 8);
    *(uint4*)(Bs + ((n * 256 + sl * 16) ^ ((n & 7) << 4))) = v;
  }
  __syncthreads();
  const int mrow = m0 + 16 * w + c;
  f32x4 acc[8];
#pragma unroll
  for (int i = 0; i < 8; ++i) acc[i] = f32x4{0.f, 0.f, 0.f, 0.f};
#pragma unroll
  for (int ks = 0; ks < 4; ++ks) {
    bf16x8 af = *(const bf16x8*)(xbf + (size_t)mrow * 128 + ks * 32 + 8 * lg);
#pragma unroll
    for (int nt = 0; nt < 8; ++nt) {
      int n = 16 * nt + c;
      bf16x8 bf = *(const bf16x8*)(Bs + ((n * 256 + 64 * ks + 16 * lg) ^ ((n & 7) << 4)));
      acc[nt] = __builtin_amdgcn_mfma_f32_16x16x32_bf16(af, bf, acc[nt], 0, 0, 0);
    }
  }
#pragma unroll
  for (int nt = 0; nt < 8; ++nt) {
    int col = 16 * nt + c;
#pragma unroll
    for (int r = 0; r < 4; ++r)
      Cbf[(size_t)(m0 + 16 * w + 4 * lg + r) * 128 + col] = f2bf(acc[nt][r] * kScale);
  }
}

// ---------------------------------------------------------------------------
// Fused conv(4x4/s4) -> LayerNorm -> kv GEMM.  128 blocks, 16 patches each.
// ---------------------------------------------------------------------------
__global__ __launch_bounds__(256) void convlnkv(const ushort* __restrict__ xbf,
                                                const ushort* __restrict__ swt,
                                                const float* __restrict__ sr_b,
                                                const float* __restrict__ ln_g,
                                                const float* __restrict__ ln_b,
                                                const ushort* __restrict__ kwt,
                                                ushort* __restrict__ kbf,
                                                ushort* __restrict__ vtbf,
                                                ushort* __restrict__ vbf) {
  __shared__ float Lf[16][132];                 // conv + bias, fp32
  __shared__ __align__(16) char Lbf[4096];      // LN'd bf16 [16][128], swizzled
  const int t = threadIdx.x, l = t & 63, w = t >> 6, c = l & 15, lg = l >> 4;
  const int m0 = blockIdx.x * 16;
  const int p = m0 + c;
  const int pb_ = p >> 10, hr = (p & 1023) >> 5, wr = p & 31;

  // ---- phase 1: conv ----
  f32x4 acc[2];
  acc[0] = f32x4{0.f, 0.f, 0.f, 0.f};
  acc[1] = f32x4{0.f, 0.f, 0.f, 0.f};
  for (int tp = 0; tp < 16; ++tp) {
    int ti = tp >> 2, tj = tp & 3;
    const ushort* ap =
        xbf + (size_t)((pb_ * 128 + hr * 4 + ti) * 128 + wr * 4 + tj) * 128;
#pragma unroll
    for (int ks = 0; ks < 4; ++ks) {
      bf16x8 af = *(const bf16x8*)(ap + ks * 32 + 8 * lg);
#pragma unroll
      for (int nt = 0; nt < 2; ++nt) {
        int n = w * 32 + 16 * nt + c;
        bf16x8 bf = *(const bf16x8*)(swt + (size_t)n * 2048 + tp * 128 + ks * 32 + 8 * lg);
        acc[nt] = __builtin_amdgcn_mfma_f32_16x16x32_bf16(af, bf, acc[nt], 0, 0, 0);
      }
    }
  }
#pragma unroll
  for (int nt = 0; nt < 2; ++nt)
#pragma unroll
    for (int r = 0; r < 4; ++r) {
      int col = w * 32 + 16 * nt + c;
      Lf[4 * lg + r][col] = acc[nt][r] + sr_b[col];
    }
  __syncthreads();

  // ---- phase 2: LayerNorm ----
  {
    int row = t >> 4, c8 = (t & 15) * 8;
    float v[8];
    float s = 0.f, sq = 0.f;
#pragma unroll
    for (int j = 0; j < 8; ++j) {
      v[j] = Lf[row][c8 + j];
      s += v[j]; sq += v[j] * v[j];
    }
#pragma unroll
    for (int off = 1; off < 16; off <<= 1) {
      s  += __shfl_xor(s, off, 64);
      sq += __shfl_xor(sq, off, 64);
    }
    float mu  = s * (1.f / 128.f);
    float var = sq * (1.f / 128.f) - mu * mu;
    float inv = 1.0f / sqrtf(var + 1e-5f);
    uint4 pk;
    unsigned* pu = (unsigned*)&pk;
#pragma unroll
    for (int j2 = 0; j2 < 4; ++j2) {
      float a = (v[2 * j2]     - mu) * inv * ln_g[c8 + 2 * j2]     + ln_b[c8 + 2 * j2];
      float b = (v[2 * j2 + 1] - mu) * inv * ln_g[c8 + 2 * j2 + 1] + ln_b[c8 + 2 * j2 + 1];
      pu[j2] = pack_bf16(a, b);
    }
    *(uint4*)(Lbf + ((row * 256 + c8 * 2) ^ ((row & 7) << 4))) = pk;
  }
  __syncthreads();

  // ---- phase 3: kv GEMM ----
  f32x4 a2[4];
#pragma unroll
  for (int i = 0; i < 4; ++i) a2[i] = f32x4{0.f, 0.f, 0.f, 0.f};
#pragma unroll
  for (int ks = 0; ks < 4; ++ks) {
    bf16x8 af = *(const bf16x8*)(Lbf + ((c * 256 + ks * 64 + 16 * lg) ^ ((c & 7) << 4)));
#pragma unroll
    for (int nt = 0; nt < 4; ++nt) {
      int n = w * 64 + 16 * nt + c;
      bf16x8 bf = *(const bf16x8*)(kwt + (size_t)n * 128 + ks * 32 + 8 * lg);
      a2[nt] = __builtin_amdgcn_mfma_f32_16x16x32_bf16(af, bf, a2[nt], 0, 0, 0);
    }
  }
#pragma unroll
  for (int nt = 0; nt < 4; ++nt)
#pragma unroll
    for (int r = 0; r < 4; ++r) {
      int m = m0 + 4 * lg + r;
      int b = m >> 10, tok = m & 1023;
      int n = w * 64 + 16 * nt + c;
      ushort val = f2bf(a2[nt][r]);
      if (n < 128) {
        int h = n >> 6, dl = n & 63;
        kbf[((size_t)((b * 2 + h) * 1024 + tok)) * 64 + dl] = val;
      } else {
        int d = n - 128, h = d >> 6, dl = d & 63;
        vbf[((size_t)((b * 2 + h) * 1024 + tok)) * 64 + dl] = val;
        vtbf[((size_t)((b * 2 + h) * 64 + dl)) * 1024 + tok] = val;
      }
    }
}

// ---------------------------------------------------------------------------
// MFMA flash attention v4: 64-row Q tile (grid 1024 = 4 blocks/CU, 4 waves/
// SIMD for latency hiding), no max-tracking, double-buffered K/V, 1 barrier/
// chunk, setprio around MFMA clusters; epilogue reduces xg column sums.
// LDS 40960 B = exactly 4 blocks/CU.
// ---------------------------------------------------------------------------
__global__ __launch_bounds__(256, 4) void attn_mfma(const ushort* __restrict__ qbf,
                                                    const ushort* __restrict__ kbf,
                                                    const ushort* __restrict__ vtbf,
                                                    ushort* __restrict__ xgbf,
                                                    float* __restrict__ zsums) {
  __shared__ __align__(16) char sm[40960];
  // [0,8K) K0 | [8K,16K) V0 | [16K,24K) K1 | [24K,32K) V1 | [32K,40K) P (4 x 2K)
  const int t = threadIdx.x;
  const int l = t & 63, w = t >> 6;
  const int c = l & 15, lg = l >> 4;
  const int h = blockIdx.y, b = blockIdx.z;
  const int qb = blockIdx.x * 64;
  char* Pw = sm + 32768 + w * 2048;
  const size_t bh = (size_t)(b * 2 + h);

  const int f0 = t, f1 = 256 + t;
  const int kk0 = f0 >> 3, sl0 = f0 & 7, kk1 = f1 >> 3, sl1 = f1 & 7;
  const int d0 = (kk0 * 128 + sl0 * 16) ^ ((kk0 & 7) << 4);
  const int d1 = (kk1 * 128 + sl1 * 16) ^ ((kk1 & 7) << 4);
  const ushort* ksrc0 = kbf + (bh * 1024 + kk0) * 64 + sl0 * 8;   // +cc*4096
  const ushort* ksrc1 = kbf + (bh * 1024 + kk1) * 64 + sl1 * 8;
  const ushort* vsrc0 = vtbf + (bh * 64 + kk0) * 1024 + sl0 * 8;  // +cc*64
  const ushort* vsrc1 = vtbf + (bh * 64 + kk1) * 1024 + sl1 * 8;

  // Q fragments: wave w owns q rows [qb+16w, qb+16w+16)
  bf16x8 qf[2];
#pragma unroll
  for (int f = 0; f < 2; ++f) {
    size_t off = ((size_t)(b * kN + qb + 16 * w + c)) * 128
                 + h * 64 + 32 * f + 8 * lg;
    qf[f] = *(const bf16x8*)(qbf + off);
  }

  float l_run = 0.f;
  f32x4 o[4] = {};   // [dt]

  {
    uint4 k0 = *(const uint4*)ksrc0;
    uint4 k1 = *(const uint4*)ksrc1;
    uint4 v0 = *(const uint4*)vsrc0;
    uint4 v1 = *(const uint4*)vsrc1;
    *(uint4*)(sm + d0) = k0;        *(uint4*)(sm + d1) = k1;
    *(uint4*)(sm + 8192 + d0) = v0; *(uint4*)(sm + 8192 + d1) = v1;
  }
  __syncthreads();

  int cur = 0;
  for (int cc = 0; cc < 16; ++cc) {
    char* Kb = sm + cur * 16384;
    char* Vb = Kb + 8192;
    uint4 nk0, nk1, nv0, nv1;
    if (cc < 15) {
      nk0 = *(const uint4*)(ksrc0 + (cc + 1) * 4096);
      nk1 = *(const uint4*)(ksrc1 + (cc + 1) * 4096);
      nv0 = *(const uint4*)(vsrc0 + (cc + 1) * 64);
      nv1 = *(const uint4*)(vsrc1 + (cc + 1) * 64);
    }

    // ---- QK^T ----
    bf16x8 kf[4][2];
#pragma unroll
    for (int kt = 0; kt < 4; ++kt)
#pragma unroll
      for (int f = 0; f < 2; ++f) {
        int row = kt * 16 + c;
        kf[kt][f] = *(const bf16x8*)(Kb + ((row * 128 + 64 * f + 16 * lg)
                                           ^ ((row & 7) << 4)));
      }
    f32x4 s4[4];
    __builtin_amdgcn_s_setprio(1);
#pragma unroll
    for (int kt = 0; kt < 4; ++kt) {
      f32x4 z = {0.f, 0.f, 0.f, 0.f};
      z = __builtin_amdgcn_mfma_f32_16x16x32_bf16(kf[kt][0], qf[0], z, 0, 0, 0);
      s4[kt] = __builtin_amdgcn_mfma_f32_16x16x32_bf16(kf[kt][1], qf[1], z, 0, 0, 0);
    }
    __builtin_amdgcn_s_setprio(0);

    // ---- exp + row-sum + P write ----
    float psum = 0.f;
#pragma unroll
    for (int kt = 0; kt < 4; ++kt)
#pragma unroll
      for (int r = 0; r < 4; ++r) {
        float p = __expf(s4[kt][r]);
        s4[kt][r] = p; psum += p;
      }
    psum += __shfl_xor(psum, 16, 64);
    psum += __shfl_xor(psum, 32, 64);
    l_run += psum;
    {
      int qq = c;
#pragma unroll
      for (int kt = 0; kt < 4; ++kt) {
        uint2 pk2;
        pk2.x = pack_bf16(s4[kt][0], s4[kt][1]);
        pk2.y = pack_bf16(s4[kt][2], s4[kt][3]);
        *(uint2*)(Pw + ((qq * 128 + 32 * kt + 8 * lg) ^ ((qq & 7) << 4))) = pk2;
      }
    }

    // ---- PV ----
    bf16x8 pf[2];
#pragma unroll
    for (int hh = 0; hh < 2; ++hh) {
      int qq = c;
      pf[hh] = *(const bf16x8*)(Pw + ((qq * 128 + 64 * hh + 16 * lg)
                                      ^ ((qq & 7) << 4)));
    }
#pragma unroll
    for (int dt = 0; dt < 4; ++dt) {
      bf16x8 vf[2];
#pragma unroll
      for (int hh = 0; hh < 2; ++hh) {
        int row = 16 * dt + c;
        vf[hh] = *(const bf16x8*)(Vb + ((row * 128 + 64 * hh + 16 * lg)
                                        ^ ((row & 7) << 4)));
      }
      __builtin_amdgcn_s_setprio(1);
      f32x4 acc = o[dt];
      acc = __builtin_amdgcn_mfma_f32_16x16x32_bf16(pf[0], vf[0], acc, 0, 0, 0);
      o[dt] = __builtin_amdgcn_mfma_f32_16x16x32_bf16(pf[1], vf[1], acc, 0, 0, 0);
      __builtin_amdgcn_s_setprio(0);
    }

    if (cc < 15) {
      char* Kn = sm + (cur ^ 1) * 16384;
      char* Vn = Kn + 8192;
      *(uint4*)(Kn + d0) = nk0; *(uint4*)(Kn + d1) = nk1;
      *(uint4*)(Vn + d0) = nv0; *(uint4*)(Vn + d1) = nv1;
    }
    __syncthreads();
    cur ^= 1;
  }

  // ---- epilogue: normalize, store bf16, reduce column sums ----
  float i0 = 1.f / __shfl(l_run, 4 * lg + 0, 64);
  float i1 = 1.f / __shfl(l_run, 4 * lg + 1, 64);
  float i2 = 1.f / __shfl(l_run, 4 * lg + 2, 64);
  float i3 = 1.f / __shfl(l_run, 4 * lg + 3, 64);
  float cs[4];
#pragma unroll
  for (int dt = 0; dt < 4; ++dt) {
    float v0 = o[dt][0] * i0, v1 = o[dt][1] * i1;
    float v2 = o[dt][2] * i2, v3 = o[dt][3] * i3;
    int dg = h * 64 + 16 * dt + c;
    size_t base = ((size_t)(b * kN + qb + 16 * w + 4 * lg)) * 128 + dg;
    xgbf[base]       = f2bf(v0);
    xgbf[base + 128] = f2bf(v1);
    xgbf[base + 256] = f2bf(v2);
    xgbf[base + 384] = f2bf(v3);
    cs[dt] = v0 + v1 + v2 + v3;
  }
#pragma unroll
  for (int dt = 0; dt < 4; ++dt) {
    cs[dt] += __shfl_xor(cs[dt], 16, 64);
    cs[dt] += __shfl_xor(cs[dt], 32, 64);
  }
  float* Cs = (float*)sm;   // [4 waves][64 cols] — safe after final barrier
  if (l < 16) {
#pragma unroll
    for (int dt = 0; dt < 4; ++dt) Cs[w * 64 + dt * 16 + l] = cs[dt];
  }
  __syncthreads();
  if (t < 64) {
    float s = Cs[t] + Cs[64 + t] + Cs[128 + t] + Cs[192 + t];
    atomicAdd(&zsums[b * 256 + h * 64 + t], s);
  }
}

// ---------------------------------------------------------------------------
// Local window attention (bf16 K/V inputs); also reduces xl column sums via
// sum_q xl[q][c] = sum_k (sum_q P[q][k]) * V[k][c].
// ---------------------------------------------------------------------------
__global__ __launch_bounds__(256) void local_attn(const ushort* __restrict__ qbf,
                                                  const ushort* __restrict__ kbf,
                                                  const ushort* __restrict__ vbf,
                                                  ushort* __restrict__ xlbf,
                                                  float* __restrict__ zsums) {
  __shared__ float Qw[64][132];
  __shared__ float Kw[4][132];
  __shared__ float Vw[4][132];
  __shared__ float Pw[64][4];
  __shared__ float cwp[4][4];
  const int t = threadIdx.x;
  const int l = t & 63, w = t >> 6;
  const int wi = blockIdx.x;
  const int b = wi >> 8, wrem = wi & 255, wy = wrem >> 4, wx = wrem & 15;

#pragma unroll
  for (int r = 0; r < 4; ++r) {
    int flat = r * 256 + t;              // 0..1023
    int tok = flat >> 4, g8 = (flat & 15) * 8;
    int sy = tok >> 3, sx = tok & 7;
    int n = (wy * 8 + sy) * 128 + wx * 8 + sx;
    uint4 v = *(const uint4*)(qbf + ((size_t)(b * kN + n)) * 128 + g8);
    ushort* us = (ushort*)&v;
    Qw[tok][g8 + 0] = bf2f(us[0]); Qw[tok][g8 + 1] = bf2f(us[1]);
    Qw[tok][g8 + 2] = bf2f(us[2]); Qw[tok][g8 + 3] = bf2f(us[3]);
    Qw[tok][g8 + 4] = bf2f(us[4]); Qw[tok][g8 + 5] = bf2f(us[5]);
    Qw[tok][g8 + 6] = bf2f(us[6]); Qw[tok][g8 + 7] = bf2f(us[7]);
  }
  {
    int half = t >> 7, tt = t & 127;
    int tok = tt >> 5, g = (tt & 31) * 4;
    int sy = tok >> 1, sx = tok & 1;
    int kr = (wy * 2 + sy) * 32 + wx * 2 + sx;
    int h = g >> 6, dl = g & 63;
    const ushort* src = (half ? vbf : kbf) + ((size_t)((b * 2 + h) * 1024 + kr)) * 64 + dl;
    uint2 v2 = *(const uint2*)src;
    ushort* us = (ushort*)&v2;
    float4 f = make_float4(bf2f(us[0]), bf2f(us[1]), bf2f(us[2]), bf2f(us[3]));
    if (half == 0) *(float4*)&Kw[tok][g] = f;
    else           *(float4*)&Vw[tok][g] = f;
  }
  __syncthreads();

  {
    int r = t >> 2, kk = t & 3;
    float s = 0.f;
#pragma unroll
    for (int g = 0; g < 128; g += 4) {
      float4 a  = *(const float4*)&Qw[r][g];
      float4 bb = *(const float4*)&Kw[kk][g];
      s += a.x * bb.x + a.y * bb.y + a.z * bb.z + a.w * bb.w;
    }
    float m = s;
    m = fmaxf(m, __shfl_xor(m, 1, 64));
    m = fmaxf(m, __shfl_xor(m, 2, 64));
    float e = __expf(s - m);
    float sum = e;
    sum += __shfl_xor(sum, 1, 64);
    sum += __shfl_xor(sum, 2, 64);
    Pw[r][kk] = e / sum;
  }
  __syncthreads();

  {
    float pv = Pw[t >> 2][t & 3];
    pv += __shfl_xor(pv, 4, 64);
    pv += __shfl_xor(pv, 8, 64);
    pv += __shfl_xor(pv, 16, 64);
    pv += __shfl_xor(pv, 32, 64);
    if (l < 4) cwp[w][l] = pv;
  }

  {
    int r = t >> 2, cg = (t & 3) * 32;
    float p0 = Pw[r][0], p1 = Pw[r][1], p2 = Pw[r][2], p3 = Pw[r][3];
    int sy = r >> 3, sx = r & 7;
    int n = (wy * 8 + sy) * 128 + wx * 8 + sx;
    ushort* dst = &xlbf[((size_t)(b * kN + n)) * 128 + cg];
#pragma unroll
    for (int g = 0; g < 32; g += 4) {
      float4 v0 = *(const float4*)&Vw[0][cg + g];
      float4 v1 = *(const float4*)&Vw[1][cg + g];
      float4 v2 = *(const float4*)&Vw[2][cg + g];
      float4 v3 = *(const float4*)&Vw[3][cg + g];
      float ox = p0 * v0.x + p1 * v1.x + p2 * v2.x + p3 * v3.x;
      float oy = p0 * v0.y + p1 * v1.y + p2 * v2.y + p3 * v3.y;
      float oz = p0 * v0.z + p1 * v1.z + p2 * v2.z + p3 * v3.z;
      float ow = p0 * v0.w + p1 * v1.w + p2 * v2.w + p3 * v3.w;
      uint2 pk;
      pk.x = pack_bf16(ox, oy); pk.y = pack_bf16(oz, ow);
      *(uint2*)&dst[g] = pk;
    }
  }
  __syncthreads();

  if (t < 128) {
    float p0 = cwp[0][0] + cwp[1][0] + cwp[2][0] + cwp[3][0];
    float p1 = cwp[0][1] + cwp[1][1] + cwp[2][1] + cwp[3][1];
    float p2 = cwp[0][2] + cwp[1][2] + cwp[2][2] + cwp[3][2];
    float p3 = cwp[0][3] + cwp[1][3] + cwp[2][3] + cwp[3][3];
    float s = p0 * Vw[0][t] + p1 * Vw[1][t] + p2 * Vw[2][t] + p3 * Vw[3][t];
    atomicAdd(&zsums[b * 256 + 128 + t], s);
  }
}

// Gating MLP, one block per batch element.
__global__ __launch_bounds__(256) void gate_mlp(const float* __restrict__ zsums,
                                                const float* __restrict__ f1w,
                                                const float* __restrict__ f1b,
                                                const float* __restrict__ f2w,
                                                const float* __restrict__ f2b,
                                                float* __restrict__ gates) {
  __shared__ float z[256];
  __shared__ float hbuf[64];
  int b = blockIdx.x, t = threadIdx.x;
  z[t] = zsums[b * 256 + t] * (1.0f / 16384.0f);
  __syncthreads();
  if (t < 64) {
    float a = f1b[t];
    for (int j = 0; j < 256; ++j) a += z[j] * f1w[j * 64 + t];
    hbuf[t] = fmaxf(a, 0.f);
  }
  __syncthreads();
  {
    float a = f2b[t];
    for (int j = 0; j < 64; ++j) a += hbuf[j] * f2w[j * 256 + t];
    gates[b * 256 + t] = 1.f / (1.f + __expf(-a));
  }
}

// ---------------------------------------------------------------------------
// MFMA fused gating + output projection from bf16 xg/xl.
// ---------------------------------------------------------------------------
__global__ __launch_bounds__(256) void fused_proj_mfma(const ushort* __restrict__ xgbf,
                                                       const ushort* __restrict__ xlbf,
                                                       const float* __restrict__ gates,
                                                       const ushort* __restrict__ pwt,
                                                       const float* __restrict__ pb,
                                                       float* __restrict__ out) {
  __shared__ __align__(16) char Bs[32768];
  __shared__ float Gg[128], Gl[128];
  const int t = threadIdx.x, l = t & 63, w = t >> 6, c = l & 15, lg = l >> 4;
  const int m0 = blockIdx.x * 64;
  const int b = m0 >> 14;
#pragma unroll
  for (int r = 0; r < 8; ++r) {
    int sf = r * 256 + t;
    int n = sf >> 4, sl = sf & 15;
    uint4 v = *(const uint4*)(pwt + n * 128 + sl * 8);
    *(uint4*)(Bs + ((n * 256 + sl * 16) ^ ((n & 7) << 4))) = v;
  }
  if (t < 128) Gg[t] = gates[b * 256 + t];
  else         Gl[t - 128] = gates[b * 256 + t];
  __syncthreads();
  const int mrow = m0 + 16 * w + c;
  f32x4 acc[8];
#pragma unroll
  for (int i = 0; i < 8; ++i) acc[i] = f32x4{0.f, 0.f, 0.f, 0.f};
#pragma unroll
  for (int ks = 0; ks < 4; ++ks) {
    int k8 = ks * 32 + 8 * lg;
    uint4 gv = *(const uint4*)(xgbf + (size_t)mrow * 128 + k8);
    uint4 lv = *(const uint4*)(xlbf + (size_t)mrow * 128 + k8);
    ushort* gu = (ushort*)&gv; ushort* lu = (ushort*)&lv;
    float f[8];
#pragma unroll
    for (int j = 0; j < 8; ++j)
      f[j] = Gg[k8 + j] * bf2f(gu[j]) + Gl[k8 + j] * bf2f(lu[j]);
    union { bf16x8 v; unsigned u[4]; } au;
    au.u[0] = pack_bf16(f[0], f[1]); au.u[1] = pack_bf16(f[2], f[3]);
    au.u[2] = pack_bf16(f[4], f[5]); au.u[3] = pack_bf16(f[6], f[7]);
#pragma unroll
    for (int nt = 0; nt < 8; ++nt) {
      int n = 16 * nt + c;
      bf16x8 bf = *(const bf16x8*)(Bs + ((n * 256 + 64 * ks + 16 * lg) ^ ((n & 7) << 4)));
      acc[nt] = __builtin_amdgcn_mfma_f32_16x16x32_bf16(au.v, bf, acc[nt], 0, 0, 0);
    }
  }
#pragma unroll
  for (int nt = 0; nt < 8; ++nt) {
    int col = 16 * nt + c;
    float bias = pb[col];
#pragma unroll
    for (int r = 0; r < 4; ++r)
      out[(size_t)(m0 + 16 * w + 4 * lg + r) * 128 + col] = acc[nt][r] + bias;
  }
}

extern "C" void kernel_launch(void* const* d_in, const int* in_sizes, int n_in,
                              void* d_out, int out_size, void* d_ws, size_t ws_size,
                              hipStream_t stream) {
  const float* x      = (const float*)d_in[0];
  const float* q_w    = (const float*)d_in[1];
  const float* kv_w   = (const float*)d_in[2];
  const float* sr_w   = (const float*)d_in[3];
  const float* sr_b   = (const float*)d_in[4];
  const float* ln_g   = (const float*)d_in[5];
  const float* ln_b   = (const float*)d_in[6];
  const float* proj_w = (const float*)d_in[7];
  const float* proj_b = (const float*)d_in[8];
  const float* f1_w   = (const float*)d_in[9];
  const float* f1_b   = (const float*)d_in[10];
  const float* f2_w   = (const float*)d_in[11];
  const float* f2_b   = (const float*)d_in[12];
  float* out = (float*)d_out;

  float* ws = (float*)d_ws;
  float* zsums = ws;                       //       512 f32
  float* gates = zsums + 512;              //       512 f32
  ushort* xbf  = (ushort*)(gates + 512);   // 4,194,304 bf16 (x copy)
  ushort* qbf  = xbf + 4194304;            // 4,194,304 bf16 (pre-scaled by 0.125)
  ushort* kbf  = qbf + 4194304;            //   262,144 bf16 [b,h][1024][64]
  ushort* vtbf = kbf + 262144;             //   262,144 bf16 [b,h][64][1024]
  ushort* vbf  = vtbf + 262144;            //   262,144 bf16 [b,h][1024][64]
  ushort* xgbf = vbf + 262144;             // 4,194,304 bf16
  ushort* xlbf = xgbf + 4194304;           // 4,194,304 bf16
  ushort* qwt  = xlbf + 4194304;           //    16,384 bf16 q_w^T
  ushort* pwt  = qwt + 16384;              //    16,384 bf16 proj_w^T
  ushort* kwt  = pwt + 16384;              //    32,768 bf16 kv_w^T [256][128]
  ushort* swt  = kwt + 32768;              //   262,144 bf16 sr_w^T [cout][2048]

  // 1. all preps in one launch (cast, 4 transposes, zsums zero)
  prep<<<dim3(2369), 256, 0, stream>>>(x, q_w, proj_w, kv_w, sr_w,
                                       xbf, qwt, pwt, kwt, swt, zsums);
  // 2. qbf = bf16((x @ q_w) * scale)
  gemm_q_mfma<<<dim3(512), 256, 0, stream>>>(xbf, qwt, qbf);
  // 3. conv -> LN -> kv GEMM fused (emits kbf, vtbf, vbf)
  convlnkv<<<dim3(128), 256, 0, stream>>>(xbf, swt, sr_b, ln_g, ln_b, kwt,
                                          kbf, vtbf, vbf);
  // 4. global attention (+ xg column sums): 64-row Q tiles, 4 blocks/CU
  attn_mfma<<<dim3(256, 2, 2), 256, 0, stream>>>(qbf, kbf, vtbf, xgbf, zsums);
  // 5. local window attention (+ xl column sums)
  local_attn<<<dim3(512), 256, 0, stream>>>(qbf, kbf, vbf, xlbf, zsums);
  // 6. gate MLP
  gate_mlp<<<dim3(2), 256, 0, stream>>>(zsums, f1_w, f1_b, f2_w, f2_b, gates);
  // 7. fused gating + output projection
  fused_proj_mfma<<<dim3(512), 256, 0, stream>>>(xgbf, xlbf, gates, pwt, proj_b, out);
}